// Round 5
// baseline (1417.614 us; speedup 1.0000x reference)
//
#include <hip/hip_runtime.h>

// Problem: B=2, H=16, S=2048, D=128
//   k_t = k.reshape(b,h,d,s)        -> QK B-operand = k slice read with ldb=S
//   score = softmax over HEAD axis (axis=1) of where(mask==0, -1e-12, q@k_t/sqrt(D))
//           (mask identical across heads -> masked positions = exactly 1/16;
//            implemented branchlessly: mask==0 -> 0 for all 16 heads)
//   out = score @ v
//   d_out = [out (8388608 f32)][score (134217728 f32)]
//
// Structure: K12 = fused QK^T + head-softmax (writes final score once,
// deletes the old K2's 1.07 GB read+write); K3 = score @ v (unchanged GEMM).

#define SS 2048
#define DD 128
#define HH 16
#define BB 2

typedef short bf16x8 __attribute__((ext_vector_type(8)));
typedef float f32x4 __attribute__((ext_vector_type(4)));

__device__ __forceinline__ unsigned short f2bf(float f) {
  union { float f; unsigned u; } x; x.f = f;
  unsigned u = x.u;
  unsigned r = u + 0x7fffu + ((u >> 16) & 1u);   // RN-even to bf16
  return (unsigned short)(r >> 16);
}

// ---------------------------------------------------------------------------
// K12: fused QK^T (all 16 heads) + mask + head-axis softmax.
// Block = 32x32 (i,j) tile, 4 waves 2x2, each wave owns a 16x16 sub-tile and
// computes it for ALL 16 heads (acc[16] f32x4). Heads staged 2 at a time
// through LDS. 1D grid 8192 with XCD-aware swizzle (j fastest within chunk).
// MFMA fragment layouts (m89-verified, validated by round-0 pass):
//   A: row=lane&15, k=(lane>>4)*8+e ; B: col=lane&15, same k
//   D: col=lane&15, row=(lane>>4)*4+reg
// ---------------------------------------------------------------------------
__global__ __launch_bounds__(256)
void qk_softmax_fused(const float* __restrict__ q, const float* __restrict__ k,
                      const int* __restrict__ mask, float* __restrict__ score)
{
  constexpr int LK = DD + 8;   // 136 shorts row stride
  const int flat = blockIdx.x;                 // 0..8191
  const int swz  = (flat & 7) * 1024 + (flat >> 3);
  const int jt = swz & 63;
  const int it = (swz >> 6) & 63;
  const int b  = swz >> 12;
  const int i0 = it * 32;
  const int j0 = jt * 32;

  const int tid  = threadIdx.x;
  const int lane = tid & 63;
  const int wv   = tid >> 6;
  const int wi16 = (wv >> 1) * 16;
  const int wj16 = (wv & 1) * 16;
  const int l15  = lane & 15;
  const int lhi  = lane >> 4;

  const float* qb = q + (long)b * HH * SS * DD;
  const float* kb = k + (long)b * HH * SS * DD;

  __shared__ unsigned short As[2][32][LK];   // [hh][i-row][k] bf16
  __shared__ unsigned short Bk[2][32][LK];   // [hh][j-col][k] bf16

  f32x4 acc[HH];
  #pragma unroll
  for (int h = 0; h < HH; ++h) acc[h] = (f32x4){0.f, 0.f, 0.f, 0.f};

  #pragma unroll
  for (int hp = 0; hp < 8; ++hp) {
    const int h0 = hp * 2;
    // ---- stage q: 2 heads x 32 rows x 128 k (fp32 -> bf16) ----
    #pragma unroll
    for (int itr = 0; itr < 8; ++itr) {
      const int idx = tid + itr * 256;        // 0..2047
      const int hh  = idx >> 10;
      const int rem = idx & 1023;
      const int row = rem >> 5;               // 0..31
      const int c4  = rem & 31;               // 0..31
      const float4 v = *reinterpret_cast<const float4*>(
          qb + ((long)(h0 + hh) * SS + (i0 + row)) * DD + c4 * 4);
      ushort4 sv;
      sv.x = f2bf(v.x); sv.y = f2bf(v.y); sv.z = f2bf(v.z); sv.w = f2bf(v.w);
      *reinterpret_cast<ushort4*>(&As[hh][row][c4 * 4]) = sv;
    }
    // ---- stage k (reshape view [D][S]): 2 heads x 128 d x 32 j, transposed ----
    #pragma unroll
    for (int itr = 0; itr < 8; ++itr) {
      const int idx = tid + itr * 256;        // 0..2047
      const int hh  = idx >> 10;
      const int rem = idx & 1023;
      const int kr  = rem >> 3;               // 0..127 (d index)
      const int j4  = rem & 7;                // 0..7
      const float4 v = *reinterpret_cast<const float4*>(
          kb + (long)(h0 + hh) * SS * DD + (long)kr * SS + j0 + j4 * 4);
      Bk[hh][j4 * 4 + 0][kr] = f2bf(v.x);
      Bk[hh][j4 * 4 + 1][kr] = f2bf(v.y);
      Bk[hh][j4 * 4 + 2][kr] = f2bf(v.z);
      Bk[hh][j4 * 4 + 3][kr] = f2bf(v.w);
    }
    __syncthreads();
    // ---- MFMA: 2 heads x 4 k-steps ----
    #pragma unroll
    for (int hh = 0; hh < 2; ++hh) {
      #pragma unroll
      for (int kk = 0; kk < 4; ++kk) {
        const int kcol = kk * 32 + lhi * 8;
        const bf16x8 af = *reinterpret_cast<const bf16x8*>(&As[hh][wi16 + l15][kcol]);
        const bf16x8 bf = *reinterpret_cast<const bf16x8*>(&Bk[hh][wj16 + l15][kcol]);
        acc[h0 + hh] = __builtin_amdgcn_mfma_f32_16x16x32_bf16(af, bf, acc[h0 + hh], 0, 0, 0);
      }
    }
    __syncthreads();
  }

  // ---- epilogue: mask + softmax across the 16 heads, per point ----
  const float scale = 0.08838834764831845f;   // 1/sqrt(128)
  const int col = j0 + wj16 + l15;
  #pragma unroll
  for (int r = 0; r < 4; ++r) {
    const int row = i0 + wi16 + lhi * 4 + r;
    const int m = mask[row * SS + col];
    const float keep = m ? scale : 0.0f;      // mask==0 -> all-equal 0 -> exact 1/16
    float sv[HH];
    float mx = -1e30f;
    #pragma unroll
    for (int h = 0; h < HH; ++h) {
      sv[h] = acc[h][r] * keep;
      mx = fmaxf(mx, sv[h]);
    }
    float sum = 0.f;
    #pragma unroll
    for (int h = 0; h < HH; ++h) {
      sv[h] = __expf(sv[h] - mx);
      sum += sv[h];
    }
    const float inv = 1.0f / sum;
    #pragma unroll
    for (int h = 0; h < HH; ++h) {
      score[(((long)b * HH + h) * SS + row) * SS + col] = sv[h] * inv;
    }
  }
}

// ---------------------------------------------------------------------------
// K3: out = score @ v. Batched C[M,N] = A[M,K] @ B[K,N], batch = blockIdx.z.
// BM=BN=128, BK=64; 256 threads = 4 waves (2x2), 4x4 fragments per wave.
// ---------------------------------------------------------------------------
__global__ __launch_bounds__(256)
void gemm_bf16(const float* __restrict__ Ag, const float* __restrict__ Bg,
               float* __restrict__ Cg, int Kdim,
               long lda, long ldb, long ldc,
               long sA, long sB, long sC, float scale)
{
  constexpr int BM = 128, BN = 128, BK = 64, LDSK = BK + 8;
  const float* A = Ag + (long)blockIdx.z * sA;
  const float* B = Bg + (long)blockIdx.z * sB;
  float*       C = Cg + (long)blockIdx.z * sC;
  const int i0 = blockIdx.x * BM;
  const int j0 = blockIdx.y * BN;
  const int tid  = threadIdx.x;
  const int lane = tid & 63;
  const int wv   = tid >> 6;
  const int wr   = (wv >> 1) * 64;
  const int wc   = (wv & 1) * 64;
  const int l15  = lane & 15;
  const int lhi  = lane >> 4;

  __shared__ unsigned short As[BM][LDSK];
  __shared__ unsigned short Bt[BN][LDSK];

  f32x4 acc[4][4];
  #pragma unroll
  for (int a = 0; a < 4; ++a)
    #pragma unroll
    for (int b2 = 0; b2 < 4; ++b2)
      acc[a][b2] = (f32x4){0.f, 0.f, 0.f, 0.f};

  for (int k0 = 0; k0 < Kdim; k0 += BK) {
    #pragma unroll
    for (int itr = 0; itr < 8; ++itr) {
      const int lin = tid + itr * 256;
      const int row = lin >> 4;
      const int c4  = lin & 15;
      const float4 v = *reinterpret_cast<const float4*>(
          A + (long)(i0 + row) * lda + (k0 + c4 * 4));
      ushort4 sv;
      sv.x = f2bf(v.x); sv.y = f2bf(v.y); sv.z = f2bf(v.z); sv.w = f2bf(v.w);
      *reinterpret_cast<ushort4*>(&As[row][c4 * 4]) = sv;
    }
    #pragma unroll
    for (int itr = 0; itr < 8; ++itr) {
      const int lin = tid + itr * 256;
      const int kr  = lin >> 5;
      const int j4  = lin & 31;
      const float4 v = *reinterpret_cast<const float4*>(
          B + (long)(k0 + kr) * ldb + (j0 + j4 * 4));
      Bt[j4 * 4 + 0][kr] = f2bf(v.x);
      Bt[j4 * 4 + 1][kr] = f2bf(v.y);
      Bt[j4 * 4 + 2][kr] = f2bf(v.z);
      Bt[j4 * 4 + 3][kr] = f2bf(v.w);
    }
    __syncthreads();
    #pragma unroll
    for (int kk = 0; kk < 2; ++kk) {
      const int kcol = kk * 32 + lhi * 8;
      bf16x8 afr[4], bfr[4];
      #pragma unroll
      for (int mi = 0; mi < 4; ++mi)
        afr[mi] = *reinterpret_cast<const bf16x8*>(&As[wr + mi * 16 + l15][kcol]);
      #pragma unroll
      for (int ni = 0; ni < 4; ++ni)
        bfr[ni] = *reinterpret_cast<const bf16x8*>(&Bt[wc + ni * 16 + l15][kcol]);
      #pragma unroll
      for (int mi = 0; mi < 4; ++mi)
        #pragma unroll
        for (int ni = 0; ni < 4; ++ni)
          acc[mi][ni] = __builtin_amdgcn_mfma_f32_16x16x32_bf16(
              afr[mi], bfr[ni], acc[mi][ni], 0, 0, 0);
    }
    __syncthreads();
  }

  #pragma unroll
  for (int mi = 0; mi < 4; ++mi) {
    #pragma unroll
    for (int ni = 0; ni < 4; ++ni) {
      const int col = j0 + wc + ni * 16 + l15;
      #pragma unroll
      for (int r = 0; r < 4; ++r) {
        const int row = i0 + wr + mi * 16 + lhi * 4 + r;
        C[(long)row * ldc + col] = acc[mi][ni][r] * scale;
      }
    }
  }
}

extern "C" void kernel_launch(void* const* d_in, const int* in_sizes, int n_in,
                              void* d_out, int out_size, void* d_ws, size_t ws_size,
                              hipStream_t stream)
{
  const float* q  = (const float*)d_in[0];
  const float* k  = (const float*)d_in[1];
  const float* v  = (const float*)d_in[2];
  const int* mask = (const int*)d_in[3];

  float* out   = (float*)d_out;
  float* score = out + (long)BB * HH * SS * DD;

  const long sQK = (long)SS * DD;
  const long sSC = (long)SS * SS;

  // K12: fused QK^T + mask + head-softmax -> writes final score once.
  qk_softmax_fused<<<dim3(64 * 64 * BB), 256, 0, stream>>>(q, k, mask, score);

  // K3: out = score @ v
  gemm_bf16<<<dim3(SS / 128, DD / 128, BB * HH), 256, 0, stream>>>(
      score, v, out, SS,
      (long)SS, (long)DD, (long)DD,
      sSC, sQK, sQK, 1.0f);
}

// Round 7
// 1306.630 us; speedup vs baseline: 1.0849x; 1.0849x over previous
//
#include <hip/hip_runtime.h>

// Problem: B=2, H=16, S=2048, D=128
//   k_t = k.reshape(b,h,d,s)        -> QK B-operand = k slice read with ldb=S
//   score = softmax over HEAD axis (axis=1) of where(mask==0, -1e-12, q@k_t/sqrt(D))
//           (mask identical across heads -> masked positions = exactly 1/16;
//            implemented branchlessly: mask==0 -> 0 for all 16 heads)
//   out = score @ v
//   d_out = [out (8388608 f32)][score (134217728 f32)]
//
// Round-5 changes (theory-first, two independent measured defects):
//  (a) L2-aware block order: each XCD owns an it-band of 8; within it, 8x8
//      (it,jt) groups -> q-strip L2-resident, k streamed once per band.
//      (was: jt-fastest -> k refetched ~16x; FETCH 932 MB)
//  (b) k-staging via 4x4 register transpose + ushort4 LDS writes
//      (was: 4 scalar u16 scatter writes, 8-way bank conflict, 6.7e7 cycles)

#define SS 2048
#define DD 128
#define HH 16
#define BB 2

typedef short bf16x8 __attribute__((ext_vector_type(8)));
typedef float f32x4 __attribute__((ext_vector_type(4)));

__device__ __forceinline__ unsigned short f2bf(float f) {
  union { float f; unsigned u; } x; x.f = f;
  unsigned u = x.u;
  unsigned r = u + 0x7fffu + ((u >> 16) & 1u);   // RN-even to bf16
  return (unsigned short)(r >> 16);
}

// ---------------------------------------------------------------------------
// K12: fused QK^T (all 16 heads) + mask + head-axis softmax.
// Block = 32x32 (i,j) tile, 4 waves 2x2, each wave owns a 16x16 sub-tile for
// ALL 16 heads (acc[16] f32x4). Heads staged 2 at a time through LDS.
// MFMA fragment layouts (m89-verified, validated by passing rounds):
//   A: row=lane&15, k=(lane>>4)*8+e ; B: col=lane&15, same k
//   D: col=lane&15, row=(lane>>4)*4+reg
// ---------------------------------------------------------------------------
__global__ __launch_bounds__(256)
void qk_softmax_fused(const float* __restrict__ q, const float* __restrict__ k,
                      const int* __restrict__ mask, float* __restrict__ score)
{
  constexpr int LK = DD + 8;   // 136 shorts row stride
  // L2-aware order: xcd = flat&7 (dispatch round-robin heuristic).
  // Each XCD: it-band of 8 i-tiles; per b, 8 jt-groups of 8; within a group
  // it varies fastest -> k-tile reused by 8 blocks back-to-back, q-strip
  // (8 it x 256KB = 2MB) L2-resident across the whole band.
  const int flat = blockIdx.x;                 // 0..8191
  const int xcd  = flat & 7;
  const int r    = flat >> 3;                  // 0..1023
  const int b    = r >> 9;                     // 0..1
  const int r2   = r & 511;
  const int grp  = r2 >> 6;                    // 0..7 (jt group)
  const int w    = r2 & 63;
  const int it   = xcd * 8 + (w & 7);          // 0..63
  const int jt   = grp * 8 + (w >> 3);         // 0..63
  const int i0 = it * 32;
  const int j0 = jt * 32;

  const int tid  = threadIdx.x;
  const int lane = tid & 63;
  const int wv   = tid >> 6;
  const int wi16 = (wv >> 1) * 16;
  const int wj16 = (wv & 1) * 16;
  const int l15  = lane & 15;
  const int lhi  = lane >> 4;

  const float* qb = q + (long)b * HH * SS * DD;
  const float* kb = k + (long)b * HH * SS * DD;

  __shared__ unsigned short As[2][32][LK];   // [hh][i-row][k] bf16
  __shared__ unsigned short Bk[2][32][LK];   // [hh][j-col][k] bf16

  f32x4 acc[HH];
  #pragma unroll
  for (int h = 0; h < HH; ++h) acc[h] = (f32x4){0.f, 0.f, 0.f, 0.f};

  // k-staging patch coords (4x4 register transpose): thread owns patch
  // (jp: 4 j cols, dp: 4 d rows) per head.
  const int jp = tid & 7;        // 0..7  -> j = jp*4 + rr
  const int dp = tid >> 3;       // 0..31 -> d = dp*4 + c

  #pragma unroll
  for (int hp = 0; hp < 8; ++hp) {
    const int h0 = hp * 2;
    // ---- stage q: 2 heads x 32 rows x 128 k (fp32 -> bf16), ushort4 writes ----
    #pragma unroll
    for (int itr = 0; itr < 8; ++itr) {
      const int idx = tid + itr * 256;        // 0..2047
      const int hh  = idx >> 10;
      const int rem = idx & 1023;
      const int row = rem >> 5;               // 0..31
      const int c4  = rem & 31;               // 0..31
      const float4 v = *reinterpret_cast<const float4*>(
          qb + ((long)(h0 + hh) * SS + (i0 + row)) * DD + c4 * 4);
      ushort4 sv;
      sv.x = f2bf(v.x); sv.y = f2bf(v.y); sv.z = f2bf(v.z); sv.w = f2bf(v.w);
      *reinterpret_cast<ushort4*>(&As[hh][row][c4 * 4]) = sv;
    }
    // ---- stage k (reshape view [D][S]) via 4x4 register transpose ----
    #pragma unroll
    for (int hh = 0; hh < 2; ++hh) {
      const float* kh = kb + (long)(h0 + hh) * SS * DD;   // [D][S] view
      float4 ld[4];
      #pragma unroll
      for (int c = 0; c < 4; ++c)
        ld[c] = *reinterpret_cast<const float4*>(
            kh + (long)(dp * 4 + c) * SS + j0 + jp * 4);
      #pragma unroll
      for (int rr = 0; rr < 4; ++rr) {
        ushort4 sv;
        sv.x = f2bf(((const float*)&ld[0])[rr]);
        sv.y = f2bf(((const float*)&ld[1])[rr]);
        sv.z = f2bf(((const float*)&ld[2])[rr]);
        sv.w = f2bf(((const float*)&ld[3])[rr]);
        *reinterpret_cast<ushort4*>(&Bk[hh][jp * 4 + rr][dp * 4]) = sv;
      }
    }
    __syncthreads();
    // ---- MFMA: 2 heads x 4 k-steps ----
    #pragma unroll
    for (int hh = 0; hh < 2; ++hh) {
      #pragma unroll
      for (int kk = 0; kk < 4; ++kk) {
        const int kcol = kk * 32 + lhi * 8;
        const bf16x8 af = *reinterpret_cast<const bf16x8*>(&As[hh][wi16 + l15][kcol]);
        const bf16x8 bf = *reinterpret_cast<const bf16x8*>(&Bk[hh][wj16 + l15][kcol]);
        acc[h0 + hh] = __builtin_amdgcn_mfma_f32_16x16x32_bf16(af, bf, acc[h0 + hh], 0, 0, 0);
      }
    }
    __syncthreads();
  }

  // ---- epilogue: mask + softmax across the 16 heads, per point ----
  const float scale = 0.08838834764831845f;   // 1/sqrt(128)
  const int col = j0 + wj16 + l15;
  #pragma unroll
  for (int r4 = 0; r4 < 4; ++r4) {
    const int row = i0 + wi16 + lhi * 4 + r4;
    const int m = mask[row * SS + col];
    const float keep = m ? scale : 0.0f;      // mask==0 -> all-equal 0 -> exact 1/16
    float sv[HH];
    float mx = -1e30f;
    #pragma unroll
    for (int h = 0; h < HH; ++h) {
      sv[h] = acc[h][r4] * keep;
      mx = fmaxf(mx, sv[h]);
    }
    float sum = 0.f;
    #pragma unroll
    for (int h = 0; h < HH; ++h) {
      sv[h] = __expf(sv[h] - mx);
      sum += sv[h];
    }
    const float inv = 1.0f / sum;
    #pragma unroll
    for (int h = 0; h < HH; ++h) {
      score[(((long)b * HH + h) * SS + row) * SS + col] = sv[h] * inv;
    }
  }
}

// ---------------------------------------------------------------------------
// K3: out = score @ v. Batched C[M,N] = A[M,K] @ B[K,N], batch = blockIdx.z.
// BM=BN=128, BK=64; 256 threads = 4 waves (2x2), 4x4 fragments per wave.
// ---------------------------------------------------------------------------
__global__ __launch_bounds__(256)
void gemm_bf16(const float* __restrict__ Ag, const float* __restrict__ Bg,
               float* __restrict__ Cg, int Kdim,
               long lda, long ldb, long ldc,
               long sA, long sB, long sC, float scale)
{
  constexpr int BM = 128, BN = 128, BK = 64, LDSK = BK + 8;
  const float* A = Ag + (long)blockIdx.z * sA;
  const float* B = Bg + (long)blockIdx.z * sB;
  float*       C = Cg + (long)blockIdx.z * sC;
  const int i0 = blockIdx.x * BM;
  const int j0 = blockIdx.y * BN;
  const int tid  = threadIdx.x;
  const int lane = tid & 63;
  const int wv   = tid >> 6;
  const int wr   = (wv >> 1) * 64;
  const int wc   = (wv & 1) * 64;
  const int l15  = lane & 15;
  const int lhi  = lane >> 4;

  __shared__ unsigned short As[BM][LDSK];
  __shared__ unsigned short Bt[BN][LDSK];

  f32x4 acc[4][4];
  #pragma unroll
  for (int a = 0; a < 4; ++a)
    #pragma unroll
    for (int b2 = 0; b2 < 4; ++b2)
      acc[a][b2] = (f32x4){0.f, 0.f, 0.f, 0.f};

  for (int k0 = 0; k0 < Kdim; k0 += BK) {
    #pragma unroll
    for (int itr = 0; itr < 8; ++itr) {
      const int lin = tid + itr * 256;
      const int row = lin >> 4;
      const int c4  = lin & 15;
      const float4 v = *reinterpret_cast<const float4*>(
          A + (long)(i0 + row) * lda + (k0 + c4 * 4));
      ushort4 sv;
      sv.x = f2bf(v.x); sv.y = f2bf(v.y); sv.z = f2bf(v.z); sv.w = f2bf(v.w);
      *reinterpret_cast<ushort4*>(&As[row][c4 * 4]) = sv;
    }
    #pragma unroll
    for (int itr = 0; itr < 8; ++itr) {
      const int lin = tid + itr * 256;
      const int kr  = lin >> 5;
      const int j4  = lin & 31;
      const float4 v = *reinterpret_cast<const float4*>(
          B + (long)(k0 + kr) * ldb + (j0 + j4 * 4));
      Bt[j4 * 4 + 0][kr] = f2bf(v.x);
      Bt[j4 * 4 + 1][kr] = f2bf(v.y);
      Bt[j4 * 4 + 2][kr] = f2bf(v.z);
      Bt[j4 * 4 + 3][kr] = f2bf(v.w);
    }
    __syncthreads();
    #pragma unroll
    for (int kk = 0; kk < 2; ++kk) {
      const int kcol = kk * 32 + lhi * 8;
      bf16x8 afr[4], bfr[4];
      #pragma unroll
      for (int mi = 0; mi < 4; ++mi)
        afr[mi] = *reinterpret_cast<const bf16x8*>(&As[wr + mi * 16 + l15][kcol]);
      #pragma unroll
      for (int ni = 0; ni < 4; ++ni)
        bfr[ni] = *reinterpret_cast<const bf16x8*>(&Bt[wc + ni * 16 + l15][kcol]);
      #pragma unroll
      for (int mi = 0; mi < 4; ++mi)
        #pragma unroll
        for (int ni = 0; ni < 4; ++ni)
          acc[mi][ni] = __builtin_amdgcn_mfma_f32_16x16x32_bf16(
              afr[mi], bfr[ni], acc[mi][ni], 0, 0, 0);
    }
    __syncthreads();
  }

  #pragma unroll
  for (int mi = 0; mi < 4; ++mi) {
    #pragma unroll
    for (int ni = 0; ni < 4; ++ni) {
      const int col = j0 + wc + ni * 16 + l15;
      #pragma unroll
      for (int r = 0; r < 4; ++r) {
        const int row = i0 + wr + mi * 16 + lhi * 4 + r;
        C[(long)row * ldc + col] = acc[mi][ni][r] * scale;
      }
    }
  }
}

extern "C" void kernel_launch(void* const* d_in, const int* in_sizes, int n_in,
                              void* d_out, int out_size, void* d_ws, size_t ws_size,
                              hipStream_t stream)
{
  const float* q  = (const float*)d_in[0];
  const float* k  = (const float*)d_in[1];
  const float* v  = (const float*)d_in[2];
  const int* mask = (const int*)d_in[3];

  float* out   = (float*)d_out;
  float* score = out + (long)BB * HH * SS * DD;

  const long sQK = (long)SS * DD;
  const long sSC = (long)SS * SS;

  // K12: fused QK^T + mask + head-softmax -> writes final score once.
  qk_softmax_fused<<<dim3(64 * 64 * BB), 256, 0, stream>>>(q, k, mask, score);

  // K3: out = score @ v
  gemm_bf16<<<dim3(SS / 128, DD / 128, BB * HH), 256, 0, stream>>>(
      score, v, out, SS,
      (long)SS, (long)DD, (long)DD,
      sSC, sQK, sQK, 1.0f);
}

// Round 8
// 1162.808 us; speedup vs baseline: 1.2191x; 1.1237x over previous
//
#include <hip/hip_runtime.h>

// B=2, H=16, S=2048, D=128
//   k_t = k.reshape(b,h,d,s)  -> QK B-operand = k slice read with ldb=S
//   score = softmax over HEAD axis of where(mask==0, -1e-12, q@k_t/sqrt(D))
//           (mask identical across heads -> masked positions exactly 1/16;
//            branchless: mask==0 -> 0 for all 16 heads)
//   out = score @ v
//   d_out = [out (8388608 f32)][score (134217728 f32)]
//
// Round-7 structure (fused K12 was latency/structure-bound: MfmaUtil 2.8%,
// HBM 19%, 16 barrier phases):
//   K1 qk_gemm        : per-head 128x128-tile GEMM, bf16 pre-scores -> d_ws
//   K2 softmax_heads  : stream bf16 pre + mask -> fp32 final score (head axis)
//   K3 gemm_bf16      : out = score @ v (unchanged)

#define SS 2048
#define DD 128
#define HH 16
#define BB 2

typedef short bf16x8 __attribute__((ext_vector_type(8)));
typedef float f32x4 __attribute__((ext_vector_type(4)));

__device__ __forceinline__ unsigned short f2bf(float f) {
  union { float f; unsigned u; } x; x.f = f;
  unsigned u = x.u;
  unsigned r = u + 0x7fffu + ((u >> 16) & 1u);   // RN-even
  return (unsigned short)(r >> 16);
}
__device__ __forceinline__ float bf2f(unsigned short s) {
  union { unsigned u; float f; } x; x.u = ((unsigned)s) << 16;
  return x.f;
}

// ---------------------------------------------------------------------------
// K1: pre[b,h,i,j] = bf16( q@k_view / sqrt(D) ), one (b,h) per blockIdx.z.
// 128x128 tile, K=128 (2 phases of BK=64), 4 waves 2x2, 4x4 fragments.
// B staged via 4x4 register transpose (measured 4-way banks, vs 32-way for
// the scalar-scatter alternative).
// ---------------------------------------------------------------------------
__global__ __launch_bounds__(256)
void qk_gemm(const float* __restrict__ q, const float* __restrict__ k,
             unsigned short* __restrict__ pre)
{
  constexpr int LDSK = 72;
  const int z  = blockIdx.z;                  // b*16+h
  const float* A = q + (long)z * SS * DD;
  const float* B = k + (long)z * SS * DD;     // [D][S] reshape view
  unsigned short* C = pre + (long)z * SS * SS;
  const int i0 = blockIdx.x * 128;
  const int j0 = blockIdx.y * 128;
  const int tid  = threadIdx.x;
  const int lane = tid & 63;
  const int wv   = tid >> 6;
  const int wr   = (wv >> 1) * 64;
  const int wc   = (wv & 1) * 64;
  const int l15  = lane & 15;
  const int lhi  = lane >> 4;

  __shared__ unsigned short As[128][LDSK];    // [i-row][k]
  __shared__ unsigned short Bt[128][LDSK];    // [j-col][k]

  f32x4 acc[4][4];
  #pragma unroll
  for (int a = 0; a < 4; ++a)
    #pragma unroll
    for (int b2 = 0; b2 < 4; ++b2)
      acc[a][b2] = (f32x4){0.f, 0.f, 0.f, 0.f};

  #pragma unroll
  for (int kp = 0; kp < 2; ++kp) {
    const int k0 = kp * 64;
    // ---- stage A: 128 rows x 64 k fp32 -> bf16 ----
    #pragma unroll
    for (int it = 0; it < 8; ++it) {
      const int lin = tid + it * 256;         // 0..2047
      const int row = lin >> 4;
      const int c4  = lin & 15;
      const float4 v = *reinterpret_cast<const float4*>(
          A + (long)(i0 + row) * DD + (k0 + c4 * 4));
      ushort4 sv;
      sv.x = f2bf(v.x); sv.y = f2bf(v.y); sv.z = f2bf(v.z); sv.w = f2bf(v.w);
      *reinterpret_cast<ushort4*>(&As[row][c4 * 4]) = sv;
    }
    // ---- stage B via 4x4 register transpose: 64 d x 128 j ----
    #pragma unroll
    for (int it = 0; it < 2; ++it) {
      const int p    = tid + it * 256;        // 0..511
      const int jgrp = (p & 7) + 8 * (p >> 7);   // 0..31
      const int dgrp = (p >> 3) & 15;            // 0..15
      float4 ld[4];
      #pragma unroll
      for (int c = 0; c < 4; ++c)
        ld[c] = *reinterpret_cast<const float4*>(
            B + (long)(k0 + dgrp * 4 + c) * SS + j0 + jgrp * 4);
      #pragma unroll
      for (int rr = 0; rr < 4; ++rr) {
        ushort4 sv;
        sv.x = f2bf(((const float*)&ld[0])[rr]);
        sv.y = f2bf(((const float*)&ld[1])[rr]);
        sv.z = f2bf(((const float*)&ld[2])[rr]);
        sv.w = f2bf(((const float*)&ld[3])[rr]);
        *reinterpret_cast<ushort4*>(&Bt[jgrp * 4 + rr][dgrp * 4]) = sv;
      }
    }
    __syncthreads();
    #pragma unroll
    for (int kk = 0; kk < 2; ++kk) {
      const int kcol = kk * 32 + lhi * 8;
      bf16x8 afr[4], bfr[4];
      #pragma unroll
      for (int mi = 0; mi < 4; ++mi)
        afr[mi] = *reinterpret_cast<const bf16x8*>(&As[wr + mi * 16 + l15][kcol]);
      #pragma unroll
      for (int ni = 0; ni < 4; ++ni)
        bfr[ni] = *reinterpret_cast<const bf16x8*>(&Bt[wc + ni * 16 + l15][kcol]);
      #pragma unroll
      for (int mi = 0; mi < 4; ++mi)
        #pragma unroll
        for (int ni = 0; ni < 4; ++ni)
          acc[mi][ni] = __builtin_amdgcn_mfma_f32_16x16x32_bf16(
              afr[mi], bfr[ni], acc[mi][ni], 0, 0, 0);
    }
    __syncthreads();
  }

  const float scale = 0.08838834764831845f;   // 1/sqrt(128)
  #pragma unroll
  for (int mi = 0; mi < 4; ++mi) {
    #pragma unroll
    for (int ni = 0; ni < 4; ++ni) {
      const int col = j0 + wc + ni * 16 + l15;
      #pragma unroll
      for (int r = 0; r < 4; ++r) {
        const int row = i0 + wr + mi * 16 + lhi * 4 + r;
        C[(long)row * SS + col] = f2bf(acc[mi][ni][r] * scale);
      }
    }
  }
}

// ---------------------------------------------------------------------------
// K2: head-axis softmax. Read bf16 pre[b,h,i,j] (+mask), write fp32 score.
// Thread owns 4 consecutive j for all 16 heads. Pure HBM streamer.
// ---------------------------------------------------------------------------
__global__ __launch_bounds__(256)
void softmax_heads(const unsigned short* __restrict__ pre,
                   const int* __restrict__ mask, float* __restrict__ score)
{
  const unsigned gid = blockIdx.x * 256u + threadIdx.x;  // 0..2^21-1
  const int j4 = gid & 511;
  const int i  = (gid >> 9) & 2047;
  const int b  = gid >> 20;
  const long PL = (long)SS * SS;
  const long off = (long)b * HH * PL + (long)i * SS + j4 * 4;

  const int4 mk = *reinterpret_cast<const int4*>(mask + (long)i * SS + j4 * 4);
  const float k0 = mk.x ? 1.f : 0.f, k1 = mk.y ? 1.f : 0.f;
  const float k2 = mk.z ? 1.f : 0.f, k3 = mk.w ? 1.f : 0.f;

  float4 s[HH];
  #pragma unroll
  for (int h = 0; h < HH; ++h) {
    const ushort4 u = *reinterpret_cast<const ushort4*>(pre + off + (long)h * PL);
    s[h].x = bf2f(u.x) * k0;
    s[h].y = bf2f(u.y) * k1;
    s[h].z = bf2f(u.z) * k2;
    s[h].w = bf2f(u.w) * k3;
  }
  float4 mx = s[0];
  #pragma unroll
  for (int h = 1; h < HH; ++h) {
    mx.x = fmaxf(mx.x, s[h].x);
    mx.y = fmaxf(mx.y, s[h].y);
    mx.z = fmaxf(mx.z, s[h].z);
    mx.w = fmaxf(mx.w, s[h].w);
  }
  float4 sum = {0.f, 0.f, 0.f, 0.f};
  #pragma unroll
  for (int h = 0; h < HH; ++h) {
    s[h].x = __expf(s[h].x - mx.x);
    s[h].y = __expf(s[h].y - mx.y);
    s[h].z = __expf(s[h].z - mx.z);
    s[h].w = __expf(s[h].w - mx.w);
    sum.x += s[h].x; sum.y += s[h].y; sum.z += s[h].z; sum.w += s[h].w;
  }
  const float4 inv = {1.0f / sum.x, 1.0f / sum.y, 1.0f / sum.z, 1.0f / sum.w};
  #pragma unroll
  for (int h = 0; h < HH; ++h) {
    float4 o;
    o.x = s[h].x * inv.x; o.y = s[h].y * inv.y;
    o.z = s[h].z * inv.z; o.w = s[h].w * inv.w;
    *reinterpret_cast<float4*>(score + off + (long)h * PL) = o;
  }
}

// ---------------------------------------------------------------------------
// K3: out = score @ v. Batched; BM=BN=128, BK=64; 4 waves, 4x4 fragments.
// ---------------------------------------------------------------------------
__global__ __launch_bounds__(256)
void gemm_bf16(const float* __restrict__ Ag, const float* __restrict__ Bg,
               float* __restrict__ Cg, int Kdim,
               long lda, long ldb, long ldc,
               long sA, long sB, long sC, float scale)
{
  constexpr int BM = 128, BN = 128, BK = 64, LDSK = BK + 8;
  const float* A = Ag + (long)blockIdx.z * sA;
  const float* B = Bg + (long)blockIdx.z * sB;
  float*       C = Cg + (long)blockIdx.z * sC;
  const int i0 = blockIdx.x * BM;
  const int j0 = blockIdx.y * BN;
  const int tid  = threadIdx.x;
  const int lane = tid & 63;
  const int wv   = tid >> 6;
  const int wr   = (wv >> 1) * 64;
  const int wc   = (wv & 1) * 64;
  const int l15  = lane & 15;
  const int lhi  = lane >> 4;

  __shared__ unsigned short As[BM][LDSK];
  __shared__ unsigned short Bt[BN][LDSK];

  f32x4 acc[4][4];
  #pragma unroll
  for (int a = 0; a < 4; ++a)
    #pragma unroll
    for (int b2 = 0; b2 < 4; ++b2)
      acc[a][b2] = (f32x4){0.f, 0.f, 0.f, 0.f};

  for (int k0 = 0; k0 < Kdim; k0 += BK) {
    #pragma unroll
    for (int itr = 0; itr < 8; ++itr) {
      const int lin = tid + itr * 256;
      const int row = lin >> 4;
      const int c4  = lin & 15;
      const float4 v = *reinterpret_cast<const float4*>(
          A + (long)(i0 + row) * lda + (k0 + c4 * 4));
      ushort4 sv;
      sv.x = f2bf(v.x); sv.y = f2bf(v.y); sv.z = f2bf(v.z); sv.w = f2bf(v.w);
      *reinterpret_cast<ushort4*>(&As[row][c4 * 4]) = sv;
    }
    #pragma unroll
    for (int itr = 0; itr < 8; ++itr) {
      const int lin = tid + itr * 256;
      const int kr  = lin >> 5;
      const int j4  = lin & 31;
      const float4 v = *reinterpret_cast<const float4*>(
          B + (long)(k0 + kr) * ldb + (j0 + j4 * 4));
      Bt[j4 * 4 + 0][kr] = f2bf(v.x);
      Bt[j4 * 4 + 1][kr] = f2bf(v.y);
      Bt[j4 * 4 + 2][kr] = f2bf(v.z);
      Bt[j4 * 4 + 3][kr] = f2bf(v.w);
    }
    __syncthreads();
    #pragma unroll
    for (int kk = 0; kk < 2; ++kk) {
      const int kcol = kk * 32 + lhi * 8;
      bf16x8 afr[4], bfr[4];
      #pragma unroll
      for (int mi = 0; mi < 4; ++mi)
        afr[mi] = *reinterpret_cast<const bf16x8*>(&As[wr + mi * 16 + l15][kcol]);
      #pragma unroll
      for (int ni = 0; ni < 4; ++ni)
        bfr[ni] = *reinterpret_cast<const bf16x8*>(&Bt[wc + ni * 16 + l15][kcol]);
      #pragma unroll
      for (int mi = 0; mi < 4; ++mi)
        #pragma unroll
        for (int ni = 0; ni < 4; ++ni)
          acc[mi][ni] = __builtin_amdgcn_mfma_f32_16x16x32_bf16(
              afr[mi], bfr[ni], acc[mi][ni], 0, 0, 0);
    }
    __syncthreads();
  }

  #pragma unroll
  for (int mi = 0; mi < 4; ++mi) {
    #pragma unroll
    for (int ni = 0; ni < 4; ++ni) {
      const int col = j0 + wc + ni * 16 + l15;
      #pragma unroll
      for (int r = 0; r < 4; ++r) {
        const int row = i0 + wr + mi * 16 + lhi * 4 + r;
        C[(long)row * ldc + col] = acc[mi][ni][r] * scale;
      }
    }
  }
}

extern "C" void kernel_launch(void* const* d_in, const int* in_sizes, int n_in,
                              void* d_out, int out_size, void* d_ws, size_t ws_size,
                              hipStream_t stream)
{
  const float* q  = (const float*)d_in[0];
  const float* k  = (const float*)d_in[1];
  const float* v  = (const float*)d_in[2];
  const int* mask = (const int*)d_in[3];

  float* out   = (float*)d_out;
  float* score = out + (long)BB * HH * SS * DD;
  unsigned short* pre = (unsigned short*)d_ws;   // 268 MB bf16 pre-scores

  const long sQK = (long)SS * DD;
  const long sSC = (long)SS * SS;

  // K1: bf16 pre-scores (scaled) into workspace.
  qk_gemm<<<dim3(SS / 128, SS / 128, BB * HH), 256, 0, stream>>>(q, k, pre);

  // K2: head-axis softmax, bf16 pre -> fp32 final score.
  softmax_heads<<<dim3((BB * SS * (SS / 4)) / 256), 256, 0, stream>>>(pre, mask, score);

  // K3: out = score @ v
  gemm_bf16<<<dim3(SS / 128, DD / 128, BB * HH), 256, 0, stream>>>(
      score, v, out, SS,
      (long)SS, (long)DD, (long)DD,
      sSC, sQK, sQK, 1.0f);
}